// Round 5
// baseline (962.433 us; speedup 1.0000x reference)
//
#include <hip/hip_runtime.h>
#include <hip/hip_cooperative_groups.h>
#include <math.h>

namespace cg = cooperative_groups;
typedef unsigned int uint;

#define N_ITEMS 7000
#define N_NODES 37000
#define N_USERS 30000
#define DIM     128
#define HD      64
#define NREL    10
#define NBASES  8
#define BATCH   512
#define CTXL    100
#define E_MAX   400000

#define NBLK    512
#define NTHR    256
#define NTHREADS_TOT (NBLK * NTHR)
#define NW      (NTHREADS_TOT / 64)   // 2048 waves

// scan tiling
#define NT_I 28      // ceil(7000/256)
#define NT_U 118     // ceil(30000/256)
#define NT   (NT_I + NT_U)

// ---- workspace layout (4-byte element offsets) ----
#define OFF_CNT    0
#define OFF_ICNT   (OFF_CNT + N_USERS * NREL)
#define OFF_UCNT   (OFF_ICNT + N_ITEMS)
#define ZERO_ELEMS (OFF_UCNT + N_USERS)
#define OFF_ICUR   ZERO_ELEMS
#define OFF_UCUR   (OFF_ICUR + N_ITEMS)
#define OFF_TSUM   (OFF_UCUR + N_USERS)
#define OFF_TOFF   (OFF_TSUM + 256)
#define OFF_ICSR   (OFF_TOFF + 256)
#define OFF_UCSR   (OFF_ICSR + E_MAX)
#define OFF_WC     (OFF_UCSR + E_MAX)
#define OFF_ACC    (OFF_WC + NREL * N_ITEMS * HD)
#define OFF_MEAN   (OFF_ACC + N_USERS * HD)
#define OFF_SCORE  (OFF_MEAN + N_ITEMS * HD)

// ---------------- bf16 pack/unpack (RNE) ----------------
__device__ __forceinline__ float2 bf2f(uint p) {
  float2 r;
  r.x = __uint_as_float(p << 16);
  r.y = __uint_as_float(p & 0xffff0000u);
  return r;
}
__device__ __forceinline__ uint f2bf(float x, float y) {
  uint a = __float_as_uint(x), b = __float_as_uint(y);
  a += 0x7fffu + ((a >> 16) & 1u);
  b += 0x7fffu + ((b >> 16) & 1u);
  return (a >> 16) | (b & 0xffff0000u);
}

// ---------------- wave reductions ----------------
__device__ __forceinline__ float wave_sum(float v) {
#pragma unroll
  for (int o = 1; o < 64; o <<= 1) v += __shfl_xor(v, o, 64);
  return v;
}
__device__ __forceinline__ float wave_max(float v) {
#pragma unroll
  for (int o = 1; o < 64; o <<= 1) v = fmaxf(v, __shfl_xor(v, o, 64));
  return v;
}
__device__ __forceinline__ int wave_sum_i(int v) {
#pragma unroll
  for (int o = 1; o < 64; o <<= 1) v += __shfl_xor(v, o, 64);
  return v;
}

struct Args {
  const int* ei;
  const int* et;
  const int* ctx0;
  const int* ctx1;
  const float* basis;
  const float* comp;
  const float* root;
  const float* bias;
  const float* attn_a;
  const float* attn_b;
  const float* fc1_w;
  const float* fc1_b;
  const float* fc2_w;
  const float* fc2_b;
  const float* efc1_w;
  const float* efc1_b;
  const float* efc2_w;
  const float* efc2_b;
  float* out;
  float* ws;
  int E;
};

// ==================== fused cooperative kernel ====================
__global__ __launch_bounds__(NTHR, 2) void k_fused(Args a) {
  cg::grid_group grid = cg::this_grid();
  __shared__ int ss[256];
  __shared__ int s4[4];

  const int tid  = threadIdx.x;
  const int gtid = blockIdx.x * NTHR + tid;
  const int wid  = gtid >> 6;
  const int lane = gtid & 63;
  const int E = a.E;

  int*  cnt   = (int*)(a.ws + OFF_CNT);
  int*  icnt  = (int*)(a.ws + OFF_ICNT);
  int*  ucnt  = (int*)(a.ws + OFF_UCNT);
  int*  icur  = (int*)(a.ws + OFF_ICUR);
  int*  ucur  = (int*)(a.ws + OFF_UCUR);
  int*  tsum  = (int*)(a.ws + OFF_TSUM);
  int*  toff  = (int*)(a.ws + OFF_TOFF);
  int*  icsr  = (int*)(a.ws + OFF_ICSR);
  int*  ucsr  = (int*)(a.ws + OFF_UCSR);
  uint* Wc    = (uint*)(a.ws + OFF_WC);
  uint* acc   = (uint*)(a.ws + OFF_ACC);
  uint* mean  = (uint*)(a.ws + OFF_MEAN);
  float* score = a.ws + OFF_SCORE;

  const float2* basis2 = (const float2*)a.basis;
  const float2* root2  = (const float2*)a.root;
  const float2* bias2  = (const float2*)a.bias;
  const float2* attnA2 = (const float2*)a.attn_a;
  const float2* attnB2 = (const float2*)a.attn_b;
  const float2* fc1w2  = (const float2*)a.fc1_w;
  const float2* fc1b2  = (const float2*)a.fc1_b;
  const float2* fc2w2  = (const float2*)a.fc2_w;
  const float2* fc2b2  = (const float2*)a.fc2_b;
  const float2* e1w2   = (const float2*)a.efc1_w;
  const float2* e1b2   = (const float2*)a.efc1_b;
  const float2* e2w2   = (const float2*)a.efc2_w;
  const float2* e2b2   = (const float2*)a.efc2_b;
  float2* out2 = (float2*)a.out;

  // ---- stage 1a: Wc = sum_b comp[r,b]*basis[b,item] (bf16) ----
  for (int i = wid; i < N_ITEMS; i += NW) {
    float2 bb[NBASES];
#pragma unroll
    for (int b = 0; b < NBASES; ++b)
      bb[b] = basis2[((size_t)b * N_NODES + i) * HD + lane];
#pragma unroll
    for (int r = 0; r < NREL; ++r) {
      float sx = 0.f, sy = 0.f;
#pragma unroll
      for (int b = 0; b < NBASES; ++b) {
        float c = a.comp[r * NBASES + b];
        sx = fmaf(c, bb[b].x, sx);
        sy = fmaf(c, bb[b].y, sy);
      }
      Wc[((size_t)r * N_ITEMS + i) * HD + lane] = f2bf(sx, sy);
    }
  }
  // ---- stage 1b: counts ----
  for (int e = gtid; e < E; e += NTHREADS_TOT) {
    int s  = a.ei[e];
    int u0 = a.ei[E + e] - N_ITEMS;
    int t  = a.et[e];
    atomicAdd(&cnt[u0 * NREL + t], 1);
    atomicAdd(&icnt[s], 1);
    atomicAdd(&ucnt[u0], 1);
  }
  grid.sync();

  // ---- stage 2 phase 1: per-tile sums ----
  if (blockIdx.x < NT) {
    int b = blockIdx.x;
    bool isU = (b >= NT_I);
    const int* arr = isU ? ucnt : icnt;
    int n = isU ? N_USERS : N_ITEMS;
    int idx = (isU ? (b - NT_I) : b) * 256 + tid;
    int v = (idx < n) ? arr[idx] : 0;
    int wsum = wave_sum_i(v);
    if ((tid & 63) == 0) s4[tid >> 6] = wsum;
    __syncthreads();
    if (tid == 0) tsum[b] = s4[0] + s4[1] + s4[2] + s4[3];
  }
  grid.sync();

  // ---- stage 2 phase 2: tile offsets (block 0) ----
  if (blockIdx.x == 0) {
    int li = -1;
    if (tid < NT_I) li = tid;
    else if (tid < NT) li = 128 + (tid - NT_I);
    ss[tid] = 0;
    __syncthreads();
    if (li >= 0) ss[li] = tsum[tid];
    __syncthreads();
    for (int o = 1; o < 128; o <<= 1) {
      int x = 0;
      if (tid >= o && ((tid < 128) == ((tid - o) < 128))) x = ss[tid - o];
      __syncthreads();
      ss[tid] += x;
      __syncthreads();
    }
    if (li >= 0) {
      int excl = 0;
      if (li != 0 && li != 128) excl = ss[li - 1];
      toff[tid] = excl;
    }
  }
  grid.sync();

  // ---- stage 2 phase 3: per-element cursors ----
  if (blockIdx.x < NT) {
    int b = blockIdx.x;
    bool isU = (b >= NT_I);
    const int* arr = isU ? ucnt : icnt;
    int* cur = isU ? ucur : icur;
    int n = isU ? N_USERS : N_ITEMS;
    int idx = (isU ? (b - NT_I) : b) * 256 + tid;
    int v = (idx < n) ? arr[idx] : 0;
    ss[tid] = v;
    __syncthreads();
    for (int o = 1; o < 256; o <<= 1) {
      int x = (tid >= o) ? ss[tid - o] : 0;
      __syncthreads();
      ss[tid] += x;
      __syncthreads();
    }
    if (idx < n) cur[idx] = ss[tid] - v + toff[b];
  }
  grid.sync();

  // ---- stage 3: fill CSR ----
  for (int e = gtid; e < E; e += NTHREADS_TOT) {
    int s  = a.ei[e];
    int u0 = a.ei[E + e] - N_ITEMS;
    int t  = a.et[e];
    icsr[atomicAdd(&icur[s], 1)] = u0;
    ucsr[atomicAdd(&ucur[u0], 1)] = s | (t << 16);
  }
  grid.sync();

  // ---- stage 4: per-user aggregate ----
  for (int u = wid; u < N_USERS; u += NW) {
    int deg  = ucnt[u];
    int base = ucur[u] - deg;
    float wl = 0.f;
    if (lane < NREL) {
      int c = cnt[u * NREL + lane];
      wl = (c > 0) ? 1.0f / (float)c : 0.0f;
    }
    float2 av[8];
#pragma unroll
    for (int k = 0; k < 8; ++k) { av[k].x = 0.f; av[k].y = 0.f; }
    for (int j0 = 0; j0 < deg; j0 += 64) {
      int m = deg - j0;
      if (m > 64) m = 64;
      int pl = (lane < m) ? ucsr[base + j0 + lane] : 0;
      int j = 0;
      for (; j + 8 <= m; j += 8) {
#pragma unroll
        for (int k = 0; k < 8; ++k) {
          int p = __shfl(pl, j + k);
          int r = p >> 16;
          float w = __shfl(wl, r);
          uint q = Wc[(size_t)(r * N_ITEMS + (p & 0xffff)) * HD + lane];
          float2 f = bf2f(q);
          av[k].x = fmaf(w, f.x, av[k].x);
          av[k].y = fmaf(w, f.y, av[k].y);
        }
      }
      for (; j < m; ++j) {
        int p = __shfl(pl, j);
        int r = p >> 16;
        float w = __shfl(wl, r);
        uint q = Wc[(size_t)(r * N_ITEMS + (p & 0xffff)) * HD + lane];
        float2 f = bf2f(q);
        av[0].x = fmaf(w, f.x, av[0].x);
        av[0].y = fmaf(w, f.y, av[0].y);
      }
    }
    float2 rt = root2[(size_t)(N_ITEMS + u) * HD + lane];
    rt.x += ((av[0].x + av[1].x) + (av[2].x + av[3].x)) +
            ((av[4].x + av[5].x) + (av[6].x + av[7].x));
    rt.y += ((av[0].y + av[1].y) + (av[2].y + av[3].y)) +
            ((av[4].y + av[5].y) + (av[6].y + av[7].y));
    acc[(size_t)u * HD + lane] = f2bf(rt.x, rt.y);
  }
  grid.sync();

  // ---- stage 5: per-item aggregate + mean + attention logit ----
  for (int i = wid; i < N_ITEMS; i += NW) {
    int deg  = icnt[i];
    int base = icur[i] - deg;
    float2 av[8];
#pragma unroll
    for (int k = 0; k < 8; ++k) { av[k].x = 0.f; av[k].y = 0.f; }
    for (int j0 = 0; j0 < deg; j0 += 64) {
      int m = deg - j0;
      if (m > 64) m = 64;
      int pl = (lane < m) ? icsr[base + j0 + lane] : 0;
      int j = 0;
      for (; j + 8 <= m; j += 8) {
#pragma unroll
        for (int k = 0; k < 8; ++k) {
          int u0 = __shfl(pl, j + k);
          float2 f = bf2f(acc[(size_t)u0 * HD + lane]);
          av[k].x += f.x;
          av[k].y += f.y;
        }
      }
      for (; j < m; ++j) {
        int u0 = __shfl(pl, j);
        float2 f = bf2f(acc[(size_t)u0 * HD + lane]);
        av[0].x += f.x;
        av[0].y += f.y;
      }
    }
    float sx = ((av[0].x + av[1].x) + (av[2].x + av[3].x)) +
               ((av[4].x + av[5].x) + (av[6].x + av[7].x));
    float sy = ((av[0].y + av[1].y) + (av[2].y + av[3].y)) +
               ((av[4].y + av[5].y) + (av[6].y + av[7].y));
    float2 mv = {0.f, 0.f};
    if (deg > 0) {
      float inv = 1.0f / (float)deg;
      float2 bv = bias2[lane];
      mv.x = sx * inv + bv.x;
      mv.y = sy * inv + bv.y;
    }
    mean[(size_t)i * HD + lane] = f2bf(mv.x, mv.y);
    float z0 = 0.f, z1 = 0.f;
#pragma unroll 8
    for (int k2 = 0; k2 < HD; ++k2) {
      float hx = __shfl(mv.x, k2);
      float hy = __shfl(mv.y, k2);
      float2 w0 = attnA2[(size_t)(2 * k2) * HD + lane];
      float2 w1 = attnA2[(size_t)(2 * k2 + 1) * HD + lane];
      z0 = fmaf(hx, w0.x, z0); z1 = fmaf(hx, w0.y, z1);
      z0 = fmaf(hy, w1.x, z0); z1 = fmaf(hy, w1.y, z1);
    }
    float2 ab = attnB2[lane];
    float v = wave_sum(tanhf(z0) * ab.x + tanhf(z1) * ab.y);
    if (lane == 0) score[i] = (deg > 0) ? v : -1e9f;
  }
  grid.sync();

  // ---- stage 6: attention pool + fc1 + fc2 per (sample, side) ----
  for (int sd = wid; sd < 2 * BATCH; sd += NW) {
    int b = sd & (BATCH - 1);
    int c = sd >> 9;
    const int* cx = (c ? a.ctx1 : a.ctx0) + (size_t)b * CTXL;
    int id0 = cx[lane];
    float e0 = (id0 >= 0) ? score[id0] : -1e9f;
    int id1 = -1;
    float e1 = -3.0e38f;
    if (lane < CTXL - 64) {
      id1 = cx[64 + lane];
      e1 = (id1 >= 0) ? score[id1] : -1e9f;
    }
    float mx = wave_max(fmaxf(e0, e1));
    float x0 = expf(e0 - mx);
    float x1 = (lane < CTXL - 64) ? expf(e1 - mx) : 0.f;
    float inv = 1.0f / wave_sum(x0 + x1);
    float w0 = (id0 >= 0) ? x0 * inv : 0.f;
    float w1 = (id1 >= 0) ? x1 * inv : 0.f;
    int i0 = (id0 >= 0) ? id0 : 0;
    int i1 = (id1 >= 0) ? id1 : 0;

    float2 av[4];
#pragma unroll
    for (int k = 0; k < 4; ++k) { av[k].x = 0.f; av[k].y = 0.f; }
    for (int j = 0; j < 64; j += 4) {
#pragma unroll
      for (int k = 0; k < 4; ++k) {
        int ii = __shfl(i0, j + k);
        float ww = __shfl(w0, j + k);
        float2 f = bf2f(mean[(size_t)ii * HD + lane]);
        av[k].x = fmaf(ww, f.x, av[k].x);
        av[k].y = fmaf(ww, f.y, av[k].y);
      }
    }
    for (int j = 0; j < CTXL - 64; j += 4) {
#pragma unroll
      for (int k = 0; k < 4; ++k) {
        int ii = __shfl(i1, j + k);
        float ww = __shfl(w1, j + k);
        float2 f = bf2f(mean[(size_t)ii * HD + lane]);
        av[k].x = fmaf(ww, f.x, av[k].x);
        av[k].y = fmaf(ww, f.y, av[k].y);
      }
    }
    float2 pool;
    pool.x = (av[0].x + av[1].x) + (av[2].x + av[3].x);
    pool.y = (av[0].y + av[1].y) + (av[2].y + av[3].y);

    float2 z = fc1b2[lane];
#pragma unroll 8
    for (int k2 = 0; k2 < HD; ++k2) {
      float hx = __shfl(pool.x, k2);
      float hy = __shfl(pool.y, k2);
      float2 wa = fc1w2[(size_t)(2 * k2) * HD + lane];
      float2 wb = fc1w2[(size_t)(2 * k2 + 1) * HD + lane];
      z.x = fmaf(hx, wa.x, z.x); z.y = fmaf(hx, wa.y, z.y);
      z.x = fmaf(hy, wb.x, z.x); z.y = fmaf(hy, wb.y, z.y);
    }
    z.x = fmaxf(z.x, 0.f);
    z.y = fmaxf(z.y, 0.f);

    float2 z2 = fc2b2[lane];
#pragma unroll 8
    for (int k2 = 0; k2 < HD; ++k2) {
      float hx = __shfl(z.x, k2);
      float hy = __shfl(z.y, k2);
      float2 wa = fc2w2[(size_t)(2 * k2) * HD + lane];
      float2 wb = fc2w2[(size_t)(2 * k2 + 1) * HD + lane];
      z2.x = fmaf(hx, wa.x, z2.x); z2.y = fmaf(hx, wa.y, z2.y);
      z2.x = fmaf(hy, wb.x, z2.x); z2.y = fmaf(hy, wb.y, z2.y);
    }
    z2.x = fmaxf(z2.x, 0.f);
    z2.y = fmaxf(z2.y, 0.f);
    out2[((size_t)(1 + c) * BATCH + b) * HD + lane] = z2;
  }
  grid.sync();

  // ---- stage 7: profile projection ----
  for (int b = wid; b < BATCH; b += NW) {
    float2 p0 = out2[((size_t)BATCH + b) * HD + lane];
    float2 p1 = out2[((size_t)2 * BATCH + b) * HD + lane];
    float2 z = e1b2[lane];
#pragma unroll 8
    for (int k2 = 0; k2 < HD; ++k2) {
      float hx = __shfl(p0.x, k2);
      float hy = __shfl(p0.y, k2);
      float2 wa = e1w2[(size_t)(2 * k2) * HD + lane];
      float2 wb = e1w2[(size_t)(2 * k2 + 1) * HD + lane];
      z.x = fmaf(hx, wa.x, z.x); z.y = fmaf(hx, wa.y, z.y);
      z.x = fmaf(hy, wb.x, z.x); z.y = fmaf(hy, wb.y, z.y);
    }
#pragma unroll 8
    for (int k2 = 0; k2 < HD; ++k2) {
      float hx = __shfl(p1.x, k2);
      float hy = __shfl(p1.y, k2);
      float2 wa = e1w2[(size_t)(DIM + 2 * k2) * HD + lane];
      float2 wb = e1w2[(size_t)(DIM + 2 * k2 + 1) * HD + lane];
      z.x = fmaf(hx, wa.x, z.x); z.y = fmaf(hx, wa.y, z.y);
      z.x = fmaf(hy, wb.x, z.x); z.y = fmaf(hy, wb.y, z.y);
    }
    z.x = fmaxf(z.x, 0.f);
    z.y = fmaxf(z.y, 0.f);

    float2 z2 = e2b2[lane];
#pragma unroll 8
    for (int k2 = 0; k2 < HD; ++k2) {
      float hx = __shfl(z.x, k2);
      float hy = __shfl(z.y, k2);
      float2 wa = e2w2[(size_t)(2 * k2) * HD + lane];
      float2 wb = e2w2[(size_t)(2 * k2 + 1) * HD + lane];
      z2.x = fmaf(hx, wa.x, z2.x); z2.y = fmaf(hx, wa.y, z2.y);
      z2.x = fmaf(hy, wb.x, z2.x); z2.y = fmaf(hy, wb.y, z2.y);
    }
    z2.x = fmaxf(z2.x, 0.f);
    z2.y = fmaxf(z2.y, 0.f);
    out2[(size_t)b * HD + lane] = z2;
  }
}

// ==================== fallback multi-kernel path (round-3, verified) ====================
__global__ __launch_bounds__(HD) void k_combine(const float* __restrict__ basis,
                                                const float* __restrict__ comp,
                                                uint* __restrict__ Wc) {
  int i = blockIdx.x, t = threadIdx.x;
  float2 bb[NBASES];
#pragma unroll
  for (int b = 0; b < NBASES; ++b)
    bb[b] = ((const float2*)(basis + ((size_t)b * N_NODES + i) * DIM))[t];
#pragma unroll
  for (int r = 0; r < NREL; ++r) {
    float sx = 0.f, sy = 0.f;
#pragma unroll
    for (int b = 0; b < NBASES; ++b) {
      float c = comp[r * NBASES + b];
      sx = fmaf(c, bb[b].x, sx);
      sy = fmaf(c, bb[b].y, sy);
    }
    Wc[((size_t)r * N_ITEMS + i) * HD + t] = f2bf(sx, sy);
  }
}

__global__ __launch_bounds__(256) void k_count(const int* __restrict__ ei,
                                               const int* __restrict__ et, int E,
                                               int* __restrict__ cnt,
                                               int* __restrict__ icnt,
                                               int* __restrict__ ucnt) {
  int e = blockIdx.x * 256 + threadIdx.x;
  if (e >= E) return;
  int s = ei[e];
  int u0 = ei[E + e] - N_ITEMS;
  int t = et[e];
  atomicAdd(&cnt[u0 * NREL + t], 1);
  atomicAdd(&icnt[s], 1);
  atomicAdd(&ucnt[u0], 1);
}

__global__ __launch_bounds__(1024) void k_scan(const int* __restrict__ icnt,
                                               const int* __restrict__ ucnt,
                                               int* __restrict__ icur,
                                               int* __restrict__ ucur) {
  __shared__ int ss[1024];
  const int* in;
  int n;
  int* cur;
  if (blockIdx.x == 0) { in = icnt; n = N_ITEMS; cur = icur; }
  else                 { in = ucnt; n = N_USERS; cur = ucur; }
  int t = threadIdx.x;
  int chunk = (n + 1023) / 1024;
  int lo = t * chunk, hi = lo + chunk;
  if (lo > n) lo = n;
  if (hi > n) hi = n;
  int s = 0;
  for (int i = lo; i < hi; ++i) s += in[i];
  ss[t] = s;
  __syncthreads();
  for (int o = 1; o < 1024; o <<= 1) {
    int v = (t >= o) ? ss[t - o] : 0;
    __syncthreads();
    ss[t] += v;
    __syncthreads();
  }
  int base = (t > 0) ? ss[t - 1] : 0;
  for (int i = lo; i < hi; ++i) { cur[i] = base; base += in[i]; }
}

__global__ __launch_bounds__(256) void k_fill(const int* __restrict__ ei,
                                              const int* __restrict__ et, int E,
                                              int* __restrict__ icur,
                                              int* __restrict__ ucur,
                                              int* __restrict__ icsr,
                                              int* __restrict__ ucsr) {
  int e = blockIdx.x * 256 + threadIdx.x;
  if (e >= E) return;
  int s = ei[e];
  int u0 = ei[E + e] - N_ITEMS;
  int t = et[e];
  icsr[atomicAdd(&icur[s], 1)] = u0;
  ucsr[atomicAdd(&ucur[u0], 1)] = s | (t << 16);
}

__global__ __launch_bounds__(HD) void k_useragg(const int* __restrict__ ucnt,
                                                const int* __restrict__ ucur,
                                                const int* __restrict__ ucsr,
                                                const int* __restrict__ cnt,
                                                const uint* __restrict__ Wc,
                                                const float* __restrict__ root,
                                                uint* __restrict__ acc) {
  int u = blockIdx.x, lane = threadIdx.x;
  int deg = ucnt[u];
  int base = ucur[u] - deg;
  float wl = 0.f;
  if (lane < NREL) {
    int c = cnt[u * NREL + lane];
    wl = (c > 0) ? 1.0f / (float)c : 0.0f;
  }
  float2 av[8];
#pragma unroll
  for (int k = 0; k < 8; ++k) { av[k].x = 0.f; av[k].y = 0.f; }
  for (int j0 = 0; j0 < deg; j0 += 64) {
    int m = deg - j0;
    if (m > 64) m = 64;
    int pl = (lane < m) ? ucsr[base + j0 + lane] : 0;
    int j = 0;
    for (; j + 8 <= m; j += 8) {
#pragma unroll
      for (int k = 0; k < 8; ++k) {
        int p = __shfl(pl, j + k);
        int r = p >> 16;
        float w = __shfl(wl, r);
        uint q = Wc[(size_t)(r * N_ITEMS + (p & 0xffff)) * HD + lane];
        float2 f = bf2f(q);
        av[k].x = fmaf(w, f.x, av[k].x);
        av[k].y = fmaf(w, f.y, av[k].y);
      }
    }
    for (; j < m; ++j) {
      int p = __shfl(pl, j);
      int r = p >> 16;
      float w = __shfl(wl, r);
      uint q = Wc[(size_t)(r * N_ITEMS + (p & 0xffff)) * HD + lane];
      float2 f = bf2f(q);
      av[0].x = fmaf(w, f.x, av[0].x);
      av[0].y = fmaf(w, f.y, av[0].y);
    }
  }
  float2 rt = ((const float2*)(root + (size_t)(N_ITEMS + u) * DIM))[lane];
  rt.x += ((av[0].x + av[1].x) + (av[2].x + av[3].x)) +
          ((av[4].x + av[5].x) + (av[6].x + av[7].x));
  rt.y += ((av[0].y + av[1].y) + (av[2].y + av[3].y)) +
          ((av[4].y + av[5].y) + (av[6].y + av[7].y));
  acc[(size_t)u * HD + lane] = f2bf(rt.x, rt.y);
}

__global__ __launch_bounds__(HD) void k_itemagg(const int* __restrict__ icnt,
                                                const int* __restrict__ icur,
                                                const int* __restrict__ icsr,
                                                const uint* __restrict__ acc,
                                                const float* __restrict__ bias,
                                                const float* __restrict__ attn_a,
                                                const float* __restrict__ attn_b,
                                                uint* __restrict__ mean,
                                                float* __restrict__ score) {
  int i = blockIdx.x, lane = threadIdx.x;
  int deg = icnt[i];
  int base = icur[i] - deg;
  float2 av[8];
#pragma unroll
  for (int k = 0; k < 8; ++k) { av[k].x = 0.f; av[k].y = 0.f; }
  for (int j0 = 0; j0 < deg; j0 += 64) {
    int m = deg - j0;
    if (m > 64) m = 64;
    int pl = (lane < m) ? icsr[base + j0 + lane] : 0;
    int j = 0;
    for (; j + 8 <= m; j += 8) {
#pragma unroll
      for (int k = 0; k < 8; ++k) {
        int u0 = __shfl(pl, j + k);
        float2 f = bf2f(acc[(size_t)u0 * HD + lane]);
        av[k].x += f.x;
        av[k].y += f.y;
      }
    }
    for (; j < m; ++j) {
      int u0 = __shfl(pl, j);
      float2 f = bf2f(acc[(size_t)u0 * HD + lane]);
      av[0].x += f.x;
      av[0].y += f.y;
    }
  }
  float sx = ((av[0].x + av[1].x) + (av[2].x + av[3].x)) +
             ((av[4].x + av[5].x) + (av[6].x + av[7].x));
  float sy = ((av[0].y + av[1].y) + (av[2].y + av[3].y)) +
             ((av[4].y + av[5].y) + (av[6].y + av[7].y));
  float2 mv = {0.f, 0.f};
  if (deg > 0) {
    float inv = 1.0f / (float)deg;
    float2 bv = ((const float2*)bias)[lane];
    mv.x = sx * inv + bv.x;
    mv.y = sy * inv + bv.y;
  }
  mean[(size_t)i * HD + lane] = f2bf(mv.x, mv.y);
  float z0 = 0.f, z1 = 0.f;
#pragma unroll 8
  for (int k2 = 0; k2 < HD; ++k2) {
    float hx = __shfl(mv.x, k2);
    float hy = __shfl(mv.y, k2);
    float2 w0 = ((const float2*)attn_a)[(size_t)(2 * k2) * HD + lane];
    float2 w1 = ((const float2*)attn_a)[(size_t)(2 * k2 + 1) * HD + lane];
    z0 = fmaf(hx, w0.x, z0); z1 = fmaf(hx, w0.y, z1);
    z0 = fmaf(hy, w1.x, z0); z1 = fmaf(hy, w1.y, z1);
  }
  float2 ab = ((const float2*)attn_b)[lane];
  float v = wave_sum(tanhf(z0) * ab.x + tanhf(z1) * ab.y);
  if (lane == 0) score[i] = (deg > 0) ? v : -1e9f;
}

__global__ __launch_bounds__(HD) void k_pool(const int* __restrict__ ctx0,
                                             const int* __restrict__ ctx1,
                                             const uint* __restrict__ mean,
                                             const float* __restrict__ score,
                                             const float* __restrict__ fc1_w,
                                             const float* __restrict__ fc1_b,
                                             const float* __restrict__ fc2_w,
                                             const float* __restrict__ fc2_b,
                                             float* __restrict__ out) {
  int b = blockIdx.x & (BATCH - 1);
  int c = blockIdx.x >> 9;
  int lane = threadIdx.x;
  const int* cx = (c ? ctx1 : ctx0) + (size_t)b * CTXL;
  int id0 = cx[lane];
  float e0 = (id0 >= 0) ? score[id0] : -1e9f;
  int id1 = -1;
  float e1 = -3.0e38f;
  if (lane < CTXL - 64) {
    id1 = cx[64 + lane];
    e1 = (id1 >= 0) ? score[id1] : -1e9f;
  }
  float mx = wave_max(fmaxf(e0, e1));
  float x0 = expf(e0 - mx);
  float x1 = (lane < CTXL - 64) ? expf(e1 - mx) : 0.f;
  float inv = 1.0f / wave_sum(x0 + x1);
  float w0 = (id0 >= 0) ? x0 * inv : 0.f;
  float w1 = (id1 >= 0) ? x1 * inv : 0.f;
  int i0 = (id0 >= 0) ? id0 : 0;
  int i1 = (id1 >= 0) ? id1 : 0;

  float2 av[4];
#pragma unroll
  for (int k = 0; k < 4; ++k) { av[k].x = 0.f; av[k].y = 0.f; }
  for (int j = 0; j < 64; j += 4) {
#pragma unroll
    for (int k = 0; k < 4; ++k) {
      int ii = __shfl(i0, j + k);
      float ww = __shfl(w0, j + k);
      float2 f = bf2f(mean[(size_t)ii * HD + lane]);
      av[k].x = fmaf(ww, f.x, av[k].x);
      av[k].y = fmaf(ww, f.y, av[k].y);
    }
  }
  for (int j = 0; j < CTXL - 64; j += 4) {
#pragma unroll
    for (int k = 0; k < 4; ++k) {
      int ii = __shfl(i1, j + k);
      float ww = __shfl(w1, j + k);
      float2 f = bf2f(mean[(size_t)ii * HD + lane]);
      av[k].x = fmaf(ww, f.x, av[k].x);
      av[k].y = fmaf(ww, f.y, av[k].y);
    }
  }
  float2 pool;
  pool.x = (av[0].x + av[1].x) + (av[2].x + av[3].x);
  pool.y = (av[0].y + av[1].y) + (av[2].y + av[3].y);

  float2 z = ((const float2*)fc1_b)[lane];
#pragma unroll 8
  for (int k2 = 0; k2 < HD; ++k2) {
    float hx = __shfl(pool.x, k2);
    float hy = __shfl(pool.y, k2);
    float2 wa = ((const float2*)fc1_w)[(size_t)(2 * k2) * HD + lane];
    float2 wb = ((const float2*)fc1_w)[(size_t)(2 * k2 + 1) * HD + lane];
    z.x = fmaf(hx, wa.x, z.x); z.y = fmaf(hx, wa.y, z.y);
    z.x = fmaf(hy, wb.x, z.x); z.y = fmaf(hy, wb.y, z.y);
  }
  z.x = fmaxf(z.x, 0.f);
  z.y = fmaxf(z.y, 0.f);

  float2 z2 = ((const float2*)fc2_b)[lane];
#pragma unroll 8
  for (int k2 = 0; k2 < HD; ++k2) {
    float hx = __shfl(z.x, k2);
    float hy = __shfl(z.y, k2);
    float2 wa = ((const float2*)fc2_w)[(size_t)(2 * k2) * HD + lane];
    float2 wb = ((const float2*)fc2_w)[(size_t)(2 * k2 + 1) * HD + lane];
    z2.x = fmaf(hx, wa.x, z2.x); z2.y = fmaf(hx, wa.y, z2.y);
    z2.x = fmaf(hy, wb.x, z2.x); z2.y = fmaf(hy, wb.y, z2.y);
  }
  z2.x = fmaxf(z2.x, 0.f);
  z2.y = fmaxf(z2.y, 0.f);
  ((float2*)out)[((size_t)(1 + c) * BATCH + b) * HD + lane] = z2;
}

__global__ __launch_bounds__(HD) void k_profile(const float* __restrict__ efc1_w,
                                                const float* __restrict__ efc1_b,
                                                const float* __restrict__ efc2_w,
                                                const float* __restrict__ efc2_b,
                                                float* __restrict__ out) {
  int b = blockIdx.x, lane = threadIdx.x;
  float2* out2 = (float2*)out;
  float2 p0 = out2[((size_t)BATCH + b) * HD + lane];
  float2 p1 = out2[((size_t)2 * BATCH + b) * HD + lane];
  float2 z = ((const float2*)efc1_b)[lane];
#pragma unroll 8
  for (int k2 = 0; k2 < HD; ++k2) {
    float hx = __shfl(p0.x, k2);
    float hy = __shfl(p0.y, k2);
    float2 wa = ((const float2*)efc1_w)[(size_t)(2 * k2) * HD + lane];
    float2 wb = ((const float2*)efc1_w)[(size_t)(2 * k2 + 1) * HD + lane];
    z.x = fmaf(hx, wa.x, z.x); z.y = fmaf(hx, wa.y, z.y);
    z.x = fmaf(hy, wb.x, z.x); z.y = fmaf(hy, wb.y, z.y);
  }
#pragma unroll 8
  for (int k2 = 0; k2 < HD; ++k2) {
    float hx = __shfl(p1.x, k2);
    float hy = __shfl(p1.y, k2);
    float2 wa = ((const float2*)efc1_w)[(size_t)(DIM + 2 * k2) * HD + lane];
    float2 wb = ((const float2*)efc1_w)[(size_t)(DIM + 2 * k2 + 1) * HD + lane];
    z.x = fmaf(hx, wa.x, z.x); z.y = fmaf(hx, wa.y, z.y);
    z.x = fmaf(hy, wb.x, z.x); z.y = fmaf(hy, wb.y, z.y);
  }
  z.x = fmaxf(z.x, 0.f);
  z.y = fmaxf(z.y, 0.f);

  float2 z2 = ((const float2*)efc2_b)[lane];
#pragma unroll 8
  for (int k2 = 0; k2 < HD; ++k2) {
    float hx = __shfl(z.x, k2);
    float hy = __shfl(z.y, k2);
    float2 wa = ((const float2*)efc2_w)[(size_t)(2 * k2) * HD + lane];
    float2 wb = ((const float2*)efc2_w)[(size_t)(2 * k2 + 1) * HD + lane];
    z2.x = fmaf(hx, wa.x, z2.x); z2.y = fmaf(hx, wa.y, z2.y);
    z2.x = fmaf(hy, wb.x, z2.x); z2.y = fmaf(hy, wb.y, z2.y);
  }
  z2.x = fmaxf(z2.x, 0.f);
  z2.y = fmaxf(z2.y, 0.f);
  out2[(size_t)b * HD + lane] = z2;
}

// ---------------- launcher ----------------
extern "C" void kernel_launch(void* const* d_in, const int* in_sizes, int n_in,
                              void* d_out, int out_size, void* d_ws, size_t ws_size,
                              hipStream_t stream) {
  Args args;
  args.ei     = (const int*)d_in[0];
  args.et     = (const int*)d_in[1];
  args.ctx0   = (const int*)d_in[2];
  args.ctx1   = (const int*)d_in[3];
  args.basis  = (const float*)d_in[4];
  args.comp   = (const float*)d_in[5];
  args.root   = (const float*)d_in[6];
  args.bias   = (const float*)d_in[7];
  args.attn_a = (const float*)d_in[8];
  args.attn_b = (const float*)d_in[9];
  args.fc1_w  = (const float*)d_in[10];
  args.fc1_b  = (const float*)d_in[11];
  args.fc2_w  = (const float*)d_in[12];
  args.fc2_b  = (const float*)d_in[13];
  args.efc1_w = (const float*)d_in[14];
  args.efc1_b = (const float*)d_in[15];
  args.efc2_w = (const float*)d_in[16];
  args.efc2_b = (const float*)d_in[17];
  args.out    = (float*)d_out;
  args.ws     = (float*)d_ws;
  args.E      = in_sizes[1];

  hipMemsetAsync(d_ws, 0, (size_t)ZERO_ELEMS * sizeof(float), stream);

  // Deterministic co-residency check (pure host query, graph-capture safe).
  int blocksPerCU = 0;
  hipError_t qerr = hipOccupancyMaxActiveBlocksPerMultiprocessor(
      &blocksPerCU, (const void*)k_fused, NTHR, 0);
  bool useCoop = (qerr == hipSuccess) && (blocksPerCU * 256 >= NBLK);

  if (useCoop) {
    void* params[1] = {&args};
    hipLaunchCooperativeKernel((const void*)k_fused, dim3(NBLK), dim3(NTHR),
                               params, 0, stream);
  } else {
    const int E = args.E;
    float* ws   = (float*)d_ws;
    int*  cnt   = (int*)(ws + OFF_CNT);
    int*  icnt  = (int*)(ws + OFF_ICNT);
    int*  ucnt  = (int*)(ws + OFF_UCNT);
    int*  icur  = (int*)(ws + OFF_ICUR);
    int*  ucur  = (int*)(ws + OFF_UCUR);
    int*  icsr  = (int*)(ws + OFF_ICSR);
    int*  ucsr  = (int*)(ws + OFF_UCSR);
    uint* Wc    = (uint*)(ws + OFF_WC);
    uint* acc   = (uint*)(ws + OFF_ACC);
    uint* mean  = (uint*)(ws + OFF_MEAN);
    float* score = ws + OFF_SCORE;
    float* out  = (float*)d_out;

    k_combine<<<N_ITEMS, HD, 0, stream>>>(args.basis, args.comp, Wc);
    k_count<<<(E + 255) / 256, 256, 0, stream>>>(args.ei, args.et, E, cnt, icnt, ucnt);
    k_scan<<<2, 1024, 0, stream>>>(icnt, ucnt, icur, ucur);
    k_fill<<<(E + 255) / 256, 256, 0, stream>>>(args.ei, args.et, E, icur, ucur, icsr, ucsr);
    k_useragg<<<N_USERS, HD, 0, stream>>>(ucnt, ucur, ucsr, cnt, Wc, args.root, acc);
    k_itemagg<<<N_ITEMS, HD, 0, stream>>>(icnt, icur, icsr, acc, args.bias,
                                          args.attn_a, args.attn_b, mean, score);
    k_pool<<<2 * BATCH, HD, 0, stream>>>(args.ctx0, args.ctx1, mean, score,
                                         args.fc1_w, args.fc1_b, args.fc2_w,
                                         args.fc2_b, out);
    k_profile<<<BATCH, HD, 0, stream>>>(args.efc1_w, args.efc1_b, args.efc2_w,
                                        args.efc2_b, out);
  }
}

// Round 6
// 463.172 us; speedup vs baseline: 2.0779x; 2.0779x over previous
//
#include <hip/hip_runtime.h>
#include <math.h>

typedef unsigned int uint;

#define N_ITEMS 7000
#define N_NODES 37000
#define N_USERS 30000
#define DIM     128
#define HD      64        // DIM/2, dims handled as packed bf16 pairs
#define NREL    10
#define NBASES  8
#define BATCH   512
#define CTXL    100
#define E_MAX   400000

// ---- workspace layout (4-byte element offsets) ----
#define OFF_CNT    0                               // N_USERS*NREL ints
#define OFF_ICNT   (OFF_CNT + N_USERS * NREL)      // N_ITEMS ints
#define OFF_UCNT   (OFF_ICNT + N_ITEMS)            // N_USERS ints
#define ZERO_ELEMS (OFF_UCNT + N_USERS)            // zero up to here (~1.35 MB)
#define OFF_ICUR   ZERO_ELEMS                      // N_ITEMS ints
#define OFF_UCUR   (OFF_ICUR + N_ITEMS)            // N_USERS ints
#define OFF_ICSR   (OFF_UCUR + N_USERS)            // E ints (user idx grouped by item)
#define OFF_UCSR   (OFF_ICSR + E_MAX)              // E ints (s | rel<<16 grouped by user)
#define OFF_WC     (OFF_UCSR + E_MAX)              // NREL*N_ITEMS*HD uints (bf16x2)
#define OFF_ACC    (OFF_WC + NREL * N_ITEMS * HD)  // N_USERS*HD uints (bf16x2)
#define OFF_MEAN   (OFF_ACC + N_USERS * HD)        // N_ITEMS*HD uints (bf16x2)
#define OFF_SCORE  (OFF_MEAN + N_ITEMS * HD)       // N_ITEMS floats

// ---------------- bf16 pack/unpack (RNE) ----------------
__device__ __forceinline__ float2 bf2f(uint p) {
  float2 r;
  r.x = __uint_as_float(p << 16);
  r.y = __uint_as_float(p & 0xffff0000u);
  return r;
}
__device__ __forceinline__ uint f2bf(float x, float y) {
  uint a = __float_as_uint(x), b = __float_as_uint(y);
  a += 0x7fffu + ((a >> 16) & 1u);
  b += 0x7fffu + ((b >> 16) & 1u);
  return (a >> 16) | (b & 0xffff0000u);
}

// ---------------- wave reductions ----------------
__device__ __forceinline__ float wave_sum(float v) {
#pragma unroll
  for (int o = 1; o < 64; o <<= 1) v += __shfl_xor(v, o, 64);
  return v;
}
__device__ __forceinline__ float wave_max(float v) {
#pragma unroll
  for (int o = 1; o < 64; o <<= 1) v = fmaxf(v, __shfl_xor(v, o, 64));
  return v;
}

// ---------------- kernel 1: combine (blocks [0,1750)) U count (rest) ----------------
#define COMBINE_BLOCKS (N_ITEMS / 4)   // 1750, 4 items per 256-thread block
__global__ __launch_bounds__(256) void k_initcomb(const float* __restrict__ basis,
                                                  const float* __restrict__ comp,
                                                  uint* __restrict__ Wc,
                                                  const int* __restrict__ ei,
                                                  const int* __restrict__ et, int E,
                                                  int* __restrict__ cnt,
                                                  int* __restrict__ icnt,
                                                  int* __restrict__ ucnt) {
  int tid = threadIdx.x;
  if (blockIdx.x < COMBINE_BLOCKS) {
    int i = blockIdx.x * 4 + (tid >> 6);
    int lane = tid & 63;
    float2 bb[NBASES];
#pragma unroll
    for (int b = 0; b < NBASES; ++b)
      bb[b] = ((const float2*)basis)[((size_t)b * N_NODES + i) * HD + lane];
#pragma unroll
    for (int r = 0; r < NREL; ++r) {
      float sx = 0.f, sy = 0.f;
#pragma unroll
      for (int b = 0; b < NBASES; ++b) {
        float c = comp[r * NBASES + b];
        sx = fmaf(c, bb[b].x, sx);
        sy = fmaf(c, bb[b].y, sy);
      }
      Wc[((size_t)r * N_ITEMS + i) * HD + lane] = f2bf(sx, sy);
    }
  } else {
    int e = (blockIdx.x - COMBINE_BLOCKS) * 256 + tid;
    if (e < E) {
      int s  = ei[e];
      int u0 = ei[E + e] - N_ITEMS;
      int t  = et[e];
      atomicAdd(&cnt[u0 * NREL + t], 1);
      atomicAdd(&icnt[s], 1);
      atomicAdd(&ucnt[u0], 1);
    }
  }
}

// ---------------- kernel 2: exclusive scans -> cursors ----------------
__global__ __launch_bounds__(1024) void k_scan(const int* __restrict__ icnt,
                                               const int* __restrict__ ucnt,
                                               int* __restrict__ icur,
                                               int* __restrict__ ucur) {
  __shared__ int ss[1024];
  const int* in;
  int n;
  int* cur;
  if (blockIdx.x == 0) { in = icnt; n = N_ITEMS; cur = icur; }
  else                 { in = ucnt; n = N_USERS; cur = ucur; }
  int t = threadIdx.x;
  int chunk = (n + 1023) / 1024;
  int lo = t * chunk, hi = lo + chunk;
  if (lo > n) lo = n;
  if (hi > n) hi = n;
  int s = 0;
  for (int i = lo; i < hi; ++i) s += in[i];
  ss[t] = s;
  __syncthreads();
  for (int o = 1; o < 1024; o <<= 1) {
    int v = (t >= o) ? ss[t - o] : 0;
    __syncthreads();
    ss[t] += v;
    __syncthreads();
  }
  int base = (t > 0) ? ss[t - 1] : 0;
  for (int i = lo; i < hi; ++i) { cur[i] = base; base += in[i]; }
}

// ---------------- kernel 3: fill CSR payloads ----------------
__global__ __launch_bounds__(256) void k_fill(const int* __restrict__ ei,
                                              const int* __restrict__ et, int E,
                                              int* __restrict__ icur,
                                              int* __restrict__ ucur,
                                              int* __restrict__ icsr,
                                              int* __restrict__ ucsr) {
  int e = blockIdx.x * 256 + threadIdx.x;
  if (e >= E) return;
  int s = ei[e];
  int u0 = ei[E + e] - N_ITEMS;
  int t = et[e];
  icsr[atomicAdd(&icur[s], 1)] = u0;
  ucsr[atomicAdd(&ucur[u0], 1)] = s | (t << 16);
}

// ---------------- kernel 4: per-user aggregate (batched padded gathers) ----------------
__global__ __launch_bounds__(64) void k_useragg(const int* __restrict__ ucnt,
                                                const int* __restrict__ ucur,
                                                const int* __restrict__ ucsr,
                                                const int* __restrict__ cnt,
                                                const uint* __restrict__ Wc,
                                                const float* __restrict__ root,
                                                uint* __restrict__ acc) {
  int u = blockIdx.x, lane = threadIdx.x;
  int deg = ucnt[u];
  int base = ucur[u] - deg;   // cursor ended at segment end
  float wl = 0.f;
  if (lane < NREL) {
    int c = cnt[u * NREL + lane];
    wl = (c > 0) ? 1.0f / (float)c : 0.0f;   // lanes >= NREL stay 0 (pad sentinel relies on it)
  }
  float2 av[8];
#pragma unroll
  for (int k = 0; k < 8; ++k) { av[k].x = 0.f; av[k].y = 0.f; }
  for (int j0 = 0; j0 < deg; j0 += 64) {
    int m = deg - j0;
    if (m > 64) m = 64;
    int pl = (lane < m) ? ucsr[base + j0 + lane] : 0;
    for (int kk = 0; kk < m; kk += 16) {
#pragma unroll
      for (int k = 0; k < 16; ++k) {
        int idx = kk + k;                 // wave-uniform
        int p = __shfl(pl, idx & 63);
        int r = p >> 16;
        // invalid slots: weight 0 (uniform predicate), load still issued from a safe row
        float w = (idx < m) ? __shfl(wl, r) : 0.f;
        uint q = Wc[(size_t)(r * N_ITEMS + (p & 0xffff)) * HD + lane];
        float2 f = bf2f(q);
        av[k & 7].x = fmaf(w, f.x, av[k & 7].x);
        av[k & 7].y = fmaf(w, f.y, av[k & 7].y);
      }
    }
  }
  float2 rt = ((const float2*)root)[(size_t)(N_ITEMS + u) * HD + lane];
  rt.x += ((av[0].x + av[1].x) + (av[2].x + av[3].x)) +
          ((av[4].x + av[5].x) + (av[6].x + av[7].x));
  rt.y += ((av[0].y + av[1].y) + (av[2].y + av[3].y)) +
          ((av[4].y + av[5].y) + (av[6].y + av[7].y));
  acc[(size_t)u * HD + lane] = f2bf(rt.x, rt.y);
}

// ---------------- kernel 5: per-item aggregate + mean + attention logit ----------------
__global__ __launch_bounds__(64) void k_itemagg(const int* __restrict__ icnt,
                                                const int* __restrict__ icur,
                                                const int* __restrict__ icsr,
                                                const uint* __restrict__ acc,
                                                const float* __restrict__ bias,
                                                const float* __restrict__ attn_a,
                                                const float* __restrict__ attn_b,
                                                uint* __restrict__ mean,
                                                float* __restrict__ score) {
  int i = blockIdx.x, lane = threadIdx.x;
  int deg = icnt[i];
  int base = icur[i] - deg;
  float2 av[8];
#pragma unroll
  for (int k = 0; k < 8; ++k) { av[k].x = 0.f; av[k].y = 0.f; }
  for (int j0 = 0; j0 < deg; j0 += 64) {
    int m = deg - j0;
    if (m > 64) m = 64;
    int pl = (lane < m) ? icsr[base + j0 + lane] : 0;
    for (int kk = 0; kk < m; kk += 16) {
#pragma unroll
      for (int k = 0; k < 16; ++k) {
        int idx = kk + k;                 // wave-uniform
        int u0 = __shfl(pl, idx & 63);
        uint q = acc[(size_t)u0 * HD + lane];
        float2 f = bf2f(q);
        if (idx < m) {                    // uniform predicate; pad contributes 0
          av[k & 7].x += f.x;
          av[k & 7].y += f.y;
        }
      }
    }
  }
  float sx = ((av[0].x + av[1].x) + (av[2].x + av[3].x)) +
             ((av[4].x + av[5].x) + (av[6].x + av[7].x));
  float sy = ((av[0].y + av[1].y) + (av[2].y + av[3].y)) +
             ((av[4].y + av[5].y) + (av[6].y + av[7].y));
  float2 mv = {0.f, 0.f};
  if (deg > 0) {
    float inv = 1.0f / (float)deg;
    float2 bv = ((const float2*)bias)[lane];
    mv.x = sx * inv + bv.x;
    mv.y = sy * inv + bv.y;
  }
  mean[(size_t)i * HD + lane] = f2bf(mv.x, mv.y);
  float z0 = 0.f, z1 = 0.f;
#pragma unroll 8
  for (int k2 = 0; k2 < HD; ++k2) {
    float hx = __shfl(mv.x, k2);
    float hy = __shfl(mv.y, k2);
    float2 w0 = ((const float2*)attn_a)[(size_t)(2 * k2) * HD + lane];
    float2 w1 = ((const float2*)attn_a)[(size_t)(2 * k2 + 1) * HD + lane];
    z0 = fmaf(hx, w0.x, z0); z1 = fmaf(hx, w0.y, z1);
    z0 = fmaf(hy, w1.x, z0); z1 = fmaf(hy, w1.y, z1);
  }
  float2 ab = ((const float2*)attn_b)[lane];
  float v = wave_sum(tanhf(z0) * ab.x + tanhf(z1) * ab.y);
  if (lane == 0) score[i] = (deg > 0) ? v : -1e9f;
}

// ---------------- kernel 6: pool + fc1 + fc2 (both sides, 2 waves) + profile ------------
__global__ __launch_bounds__(128) void k_batch2(const int* __restrict__ ctx0,
                                                const int* __restrict__ ctx1,
                                                const uint* __restrict__ mean,
                                                const float* __restrict__ score,
                                                const float* __restrict__ fc1_w,
                                                const float* __restrict__ fc1_b,
                                                const float* __restrict__ fc2_w,
                                                const float* __restrict__ fc2_b,
                                                const float* __restrict__ efc1_w,
                                                const float* __restrict__ efc1_b,
                                                const float* __restrict__ efc2_w,
                                                const float* __restrict__ efc2_b,
                                                float* __restrict__ out) {
  __shared__ float2 shp[2][HD];
  int b = blockIdx.x;
  int wv = threadIdx.x >> 6;     // side: 0 = init, 1 = resp
  int lane = threadIdx.x & 63;
  float2* out2 = (float2*)out;

  // ---- side wv: softmax over ctx, pool, fc1, fc2 (shfl-only within the wave) ----
  const int* cx = (wv ? ctx1 : ctx0) + (size_t)b * CTXL;
  int id0 = cx[lane];
  float e0 = (id0 >= 0) ? score[id0] : -1e9f;
  int id1 = -1;
  float e1 = -3.0e38f;
  if (lane < CTXL - 64) {
    id1 = cx[64 + lane];
    e1 = (id1 >= 0) ? score[id1] : -1e9f;
  }
  float mx = wave_max(fmaxf(e0, e1));
  float x0 = expf(e0 - mx);
  float x1 = (lane < CTXL - 64) ? expf(e1 - mx) : 0.f;
  float inv = 1.0f / wave_sum(x0 + x1);
  float w0 = (id0 >= 0) ? x0 * inv : 0.f;
  float w1 = (id1 >= 0) ? x1 * inv : 0.f;
  int i0 = (id0 >= 0) ? id0 : 0;
  int i1 = (id1 >= 0) ? id1 : 0;

  float2 av[4];
#pragma unroll
  for (int k = 0; k < 4; ++k) { av[k].x = 0.f; av[k].y = 0.f; }
  for (int j = 0; j < 64; j += 4) {
#pragma unroll
    for (int k = 0; k < 4; ++k) {
      int ii = __shfl(i0, j + k);
      float ww = __shfl(w0, j + k);
      float2 f = bf2f(mean[(size_t)ii * HD + lane]);
      av[k].x = fmaf(ww, f.x, av[k].x);
      av[k].y = fmaf(ww, f.y, av[k].y);
    }
  }
  for (int j = 0; j < CTXL - 64; j += 4) {
#pragma unroll
    for (int k = 0; k < 4; ++k) {
      int ii = __shfl(i1, j + k);
      float ww = __shfl(w1, j + k);
      float2 f = bf2f(mean[(size_t)ii * HD + lane]);
      av[k].x = fmaf(ww, f.x, av[k].x);
      av[k].y = fmaf(ww, f.y, av[k].y);
    }
  }
  float2 pool;
  pool.x = (av[0].x + av[1].x) + (av[2].x + av[3].x);
  pool.y = (av[0].y + av[1].y) + (av[2].y + av[3].y);

  float2 z = ((const float2*)fc1_b)[lane];
#pragma unroll 8
  for (int k2 = 0; k2 < HD; ++k2) {
    float hx = __shfl(pool.x, k2);
    float hy = __shfl(pool.y, k2);
    float2 wa = ((const float2*)fc1_w)[(size_t)(2 * k2) * HD + lane];
    float2 wb = ((const float2*)fc1_w)[(size_t)(2 * k2 + 1) * HD + lane];
    z.x = fmaf(hx, wa.x, z.x); z.y = fmaf(hx, wa.y, z.y);
    z.x = fmaf(hy, wb.x, z.x); z.y = fmaf(hy, wb.y, z.y);
  }
  z.x = fmaxf(z.x, 0.f);
  z.y = fmaxf(z.y, 0.f);

  float2 z2 = ((const float2*)fc2_b)[lane];
#pragma unroll 8
  for (int k2 = 0; k2 < HD; ++k2) {
    float hx = __shfl(z.x, k2);
    float hy = __shfl(z.y, k2);
    float2 wa = ((const float2*)fc2_w)[(size_t)(2 * k2) * HD + lane];
    float2 wb = ((const float2*)fc2_w)[(size_t)(2 * k2 + 1) * HD + lane];
    z2.x = fmaf(hx, wa.x, z2.x); z2.y = fmaf(hx, wa.y, z2.y);
    z2.x = fmaf(hy, wb.x, z2.x); z2.y = fmaf(hy, wb.y, z2.y);
  }
  z2.x = fmaxf(z2.x, 0.f);
  z2.y = fmaxf(z2.y, 0.f);
  out2[((size_t)(1 + wv) * BATCH + b) * HD + lane] = z2;   // p_init / p_resp
  shp[wv][lane] = z2;
  __syncthreads();

  // ---- profile = project(concat(p_init, p_resp)) on wave 0 ----
  if (wv == 0) {
    float2 p0 = shp[0][lane];
    float2 p1 = shp[1][lane];
    float2 zz = ((const float2*)efc1_b)[lane];
#pragma unroll 8
    for (int k2 = 0; k2 < HD; ++k2) {
      float hx = __shfl(p0.x, k2);
      float hy = __shfl(p0.y, k2);
      float2 wa = ((const float2*)efc1_w)[(size_t)(2 * k2) * HD + lane];
      float2 wb = ((const float2*)efc1_w)[(size_t)(2 * k2 + 1) * HD + lane];
      zz.x = fmaf(hx, wa.x, zz.x); zz.y = fmaf(hx, wa.y, zz.y);
      zz.x = fmaf(hy, wb.x, zz.x); zz.y = fmaf(hy, wb.y, zz.y);
    }
#pragma unroll 8
    for (int k2 = 0; k2 < HD; ++k2) {
      float hx = __shfl(p1.x, k2);
      float hy = __shfl(p1.y, k2);
      float2 wa = ((const float2*)efc1_w)[(size_t)(DIM + 2 * k2) * HD + lane];
      float2 wb = ((const float2*)efc1_w)[(size_t)(DIM + 2 * k2 + 1) * HD + lane];
      zz.x = fmaf(hx, wa.x, zz.x); zz.y = fmaf(hx, wa.y, zz.y);
      zz.x = fmaf(hy, wb.x, zz.x); zz.y = fmaf(hy, wb.y, zz.y);
    }
    zz.x = fmaxf(zz.x, 0.f);
    zz.y = fmaxf(zz.y, 0.f);

    float2 zf = ((const float2*)efc2_b)[lane];
#pragma unroll 8
    for (int k2 = 0; k2 < HD; ++k2) {
      float hx = __shfl(zz.x, k2);
      float hy = __shfl(zz.y, k2);
      float2 wa = ((const float2*)efc2_w)[(size_t)(2 * k2) * HD + lane];
      float2 wb = ((const float2*)efc2_w)[(size_t)(2 * k2 + 1) * HD + lane];
      zf.x = fmaf(hx, wa.x, zf.x); zf.y = fmaf(hx, wa.y, zf.y);
      zf.x = fmaf(hy, wb.x, zf.x); zf.y = fmaf(hy, wb.y, zf.y);
    }
    zf.x = fmaxf(zf.x, 0.f);
    zf.y = fmaxf(zf.y, 0.f);
    out2[(size_t)b * HD + lane] = zf;   // profile
  }
}

// ---------------- launcher ----------------
extern "C" void kernel_launch(void* const* d_in, const int* in_sizes, int n_in,
                              void* d_out, int out_size, void* d_ws, size_t ws_size,
                              hipStream_t stream) {
  const int*   ei     = (const int*)d_in[0];
  const int*   et     = (const int*)d_in[1];
  const int*   ctx0   = (const int*)d_in[2];
  const int*   ctx1   = (const int*)d_in[3];
  const float* basis  = (const float*)d_in[4];
  const float* comp   = (const float*)d_in[5];
  const float* root   = (const float*)d_in[6];
  const float* bias   = (const float*)d_in[7];
  const float* attn_a = (const float*)d_in[8];
  const float* attn_b = (const float*)d_in[9];
  const float* fc1_w  = (const float*)d_in[10];
  const float* fc1_b  = (const float*)d_in[11];
  const float* fc2_w  = (const float*)d_in[12];
  const float* fc2_b  = (const float*)d_in[13];
  const float* efc1_w = (const float*)d_in[14];
  const float* efc1_b = (const float*)d_in[15];
  const float* efc2_w = (const float*)d_in[16];
  const float* efc2_b = (const float*)d_in[17];
  float* out = (float*)d_out;

  const int E = in_sizes[1];

  float* ws   = (float*)d_ws;
  int*  cnt   = (int*)(ws + OFF_CNT);
  int*  icnt  = (int*)(ws + OFF_ICNT);
  int*  ucnt  = (int*)(ws + OFF_UCNT);
  int*  icur  = (int*)(ws + OFF_ICUR);
  int*  ucur  = (int*)(ws + OFF_UCUR);
  int*  icsr  = (int*)(ws + OFF_ICSR);
  int*  ucsr  = (int*)(ws + OFF_UCSR);
  uint* Wc    = (uint*)(ws + OFF_WC);
  uint* acc   = (uint*)(ws + OFF_ACC);
  uint* mean  = (uint*)(ws + OFF_MEAN);
  float* score = ws + OFF_SCORE;

  hipMemsetAsync(d_ws, 0, (size_t)ZERO_ELEMS * sizeof(float), stream);

  int countBlocks = (E + 255) / 256;
  k_initcomb<<<COMBINE_BLOCKS + countBlocks, 256, 0, stream>>>(
      basis, comp, Wc, ei, et, E, cnt, icnt, ucnt);
  k_scan<<<2, 1024, 0, stream>>>(icnt, ucnt, icur, ucur);
  k_fill<<<countBlocks, 256, 0, stream>>>(ei, et, E, icur, ucur, icsr, ucsr);
  k_useragg<<<N_USERS, 64, 0, stream>>>(ucnt, ucur, ucsr, cnt, Wc, root, acc);
  k_itemagg<<<N_ITEMS, 64, 0, stream>>>(icnt, icur, icsr, acc, bias, attn_a,
                                        attn_b, mean, score);
  k_batch2<<<BATCH, 128, 0, stream>>>(ctx0, ctx1, mean, score, fc1_w, fc1_b,
                                      fc2_w, fc2_b, efc1_w, efc1_b, efc2_w,
                                      efc2_b, out);
}